// Round 1
// baseline (1359.279 us; speedup 1.0000x reference)
//
#include <hip/hip_runtime.h>

// GroupRenderer: segment-sum of w[s]*group[s,:] over sorted ray_indices,
// then F.normalize(p=2, dim=-1) over groups of S=8.
// group: [ns, 16, 8] f32; weights: [ns,1] f32; ray_indices: [ns] i32 sorted;
// out: [num_rays, 16, 8] f32.  LS = 128 floats per sample/ray row.

#define LS 128
#define EPS 1e-12f

// starts[r] = lower_bound(ray_indices, r), r in [0, num_rays]; starts in d_ws.
__global__ void find_starts(const int* __restrict__ ray_indices, int ns,
                            int num_rays, int* __restrict__ starts) {
    int r = blockIdx.x * blockDim.x + threadIdx.x;
    if (r > num_rays) return;
    int lo = 0, hi = ns;
    while (lo < hi) {
        int mid = (lo + hi) >> 1;          // ns < 2^31, no overflow
        if (ray_indices[mid] < r) lo = mid + 1;
        else hi = mid;
    }
    starts[r] = lo;
}

// 32 threads per ray, one float4 (16B) per thread = 512B per sample row.
// Block of 256 = 8 rays. Accumulate in registers; normalize via one
// __shfl_xor (S-group of 8 floats = thread pair (t, t^1)).
__global__ __launch_bounds__(256) void accumulate_normalize(
        const float4* __restrict__ group4,   // [ns, 32] float4
        const float*  __restrict__ weights,  // [ns]
        const int*    __restrict__ starts,   // [num_rays+1]
        float4*       __restrict__ out4,     // [num_rays, 32] float4
        int num_rays) {
    const int g   = threadIdx.x & 31;                    // float4 slot in row
    const int ray = blockIdx.x * 8 + (threadIdx.x >> 5);
    if (ray >= num_rays) return;

    const int s0 = starts[ray];
    const int s1 = starts[ray + 1];

    float4 acc = make_float4(0.f, 0.f, 0.f, 0.f);
    int s = s0;
    // 2x unroll for a little ILP; loads of iter i+1 independent of iter i.
    for (; s + 1 < s1; s += 2) {
        const float  wa = weights[s];
        const float4 va = group4[(size_t)s * 32 + g];
        const float  wb = weights[s + 1];
        const float4 vb = group4[(size_t)(s + 1) * 32 + g];
        acc.x += wa * va.x; acc.y += wa * va.y;
        acc.z += wa * va.z; acc.w += wa * va.w;
        acc.x += wb * vb.x; acc.y += wb * vb.y;
        acc.z += wb * vb.z; acc.w += wb * vb.w;
    }
    if (s < s1) {
        const float  w = weights[s];
        const float4 v = group4[(size_t)s * 32 + g];
        acc.x += w * v.x; acc.y += w * v.y;
        acc.z += w * v.z; acc.w += w * v.w;
    }

    // sum of squares over the 8-float S-group: self-dot + partner (lane^1)
    float ss = acc.x * acc.x + acc.y * acc.y + acc.z * acc.z + acc.w * acc.w;
    ss += __shfl_xor(ss, 1, 64);
    const float inv = 1.0f / fmaxf(sqrtf(ss), EPS);
    acc.x *= inv; acc.y *= inv; acc.z *= inv; acc.w *= inv;

    out4[(size_t)ray * 32 + g] = acc;
}

extern "C" void kernel_launch(void* const* d_in, const int* in_sizes, int n_in,
                              void* d_out, int out_size, void* d_ws, size_t ws_size,
                              hipStream_t stream) {
    const float* group       = (const float*)d_in[0];
    const float* weights     = (const float*)d_in[1];
    const int*   ray_indices = (const int*)d_in[2];   // jax canonicalizes to i32

    const int ns       = in_sizes[0] / LS;
    const int num_rays = out_size / LS;               // 65536

    int* starts = (int*)d_ws;                         // (num_rays+1) ints

    {
        int n = num_rays + 1;
        find_starts<<<(n + 255) / 256, 256, 0, stream>>>(ray_indices, ns,
                                                         num_rays, starts);
    }
    {
        int blocks = (num_rays + 7) / 8;              // 8 rays per 256-thr block
        accumulate_normalize<<<blocks, 256, 0, stream>>>(
            (const float4*)group, weights, starts, (float4*)d_out, num_rays);
    }
}